// Round 15
// baseline (1506.025 us; speedup 1.0000x reference)
//
#include <hip/hip_runtime.h>
#include <math.h>

typedef unsigned int u32;
typedef unsigned long long u64;
typedef __attribute__((ext_vector_type(8))) short bf16x8;   // 8 bf16 = 4 VGPR
typedef __attribute__((ext_vector_type(4))) float f32x4;
typedef __attribute__((ext_vector_type(4))) int i32x4;

#define TT 256

// ---- ws byte offsets ----
#define BOFF_WT   0ULL          // bf16 [3 mat][2 pl][8 kc][1024 n][40 kpad] = 3,932,160 B
#define BOFF_WX   3932160ULL    // fp32 [10][1024] = 40,960 B
#define BOFF_H0HI 3973120ULL    // bf16 [2 slot][8 ib][32 ik][64 r][8 u] = 524,288 B each
#define BOFF_H0LO 4497408ULL
#define BOFF_H1HI 5021696ULL
#define BOFF_H1LO 5545984ULL
#define BOFF_FLG  6070272ULL    // flag region (fast sc0 lines + safe agent lines)

#define OB_H0HI 3973120u
#define OB_H0LO 4497408u
#define OB_H1HI 5021696u
#define OB_H1LO 5545984u
// fast flags (sc0, L2-resident): one 128B line per ib group, 32 u32 words
#define OB_FLGF 6070272u
// safe flags (agent scope): separate lines, +4096B
#define OB_FLGS 6074368u

// ---------------------------------------------------------------------------
// W [1024][K] row-major -> A [K][1024] gate-interleaved fp32 (for x-gemm)
__global__ void transpose_gi(const float* __restrict__ W, float* __restrict__ A, int K) {
    int idx = blockIdx.x * 256 + threadIdx.x;
    if (idx < K * 1024) {
        int kk = idx >> 10, r = idx & 1023, k = r >> 2, g = r & 3;
        A[idx] = W[(g * 256 + k) * K + kk];
    }
}

// Split fp32 weights into hi/lo bf16 planes, MFMA B-tile layout:
// wt[((mt*2+pl)*8 + kc)*1024 + n][40] , n = gate-col (u*4+g), k within chunk 0..31
__global__ void split_w(const float* __restrict__ W0, const float* __restrict__ W1,
                        const float* __restrict__ W2, unsigned short* __restrict__ wt) {
    int idx = blockIdx.x * 256 + threadIdx.x;      // 786432 total
    int k32 = idx & 31;
    int n   = (idx >> 5) & 1023;
    int kc  = (idx >> 15) & 7;
    int mt  = idx >> 18;
    const float* W = (mt == 0) ? W0 : (mt == 1) ? W1 : W2;
    int ug = n >> 2, g = n & 3, k = kc * 32 + k32;
    float v = W[(g * 256 + ug) * 256 + k];
    u32 b = __float_as_uint(v);
    unsigned short hi = (unsigned short)(b >> 16);               // truncated hi
    float lo = v - __uint_as_float(b & 0xFFFF0000u);             // exact residual
    u32 lb = __float_as_uint(lo);
    unsigned short los = (unsigned short)((lb + 0x7FFFu + ((lb >> 16) & 1u)) >> 16);
    wt[((size_t)((mt * 2 + 0) * 8 + kc) * 1024 + n) * 40 + k32] = hi;
    wt[((size_t)((mt * 2 + 1) * 8 + kc) * 1024 + n) * 40 + k32] = los;
}

__device__ __forceinline__ float sigf(float x)     { return 1.0f / (1.0f + __expf(-x)); }
__device__ __forceinline__ float tanhfast(float x) { return 1.0f - 2.0f / (__expf(2.0f * x) + 1.0f); }

__device__ __forceinline__ unsigned short bhi(float v) {
    return (unsigned short)(__float_as_uint(v) >> 16);
}
__device__ __forceinline__ unsigned short blo(float v) {
    float lo = v - __uint_as_float(__float_as_uint(v) & 0xFFFF0000u);
    u32 lb = __float_as_uint(lo);
    return (unsigned short)((lb + 0x7FFFu + ((lb >> 16) & 1u)) >> 16);
}
__device__ __forceinline__ float bff(u32 us) { return __uint_as_float(us << 16); }

// SRD over the whole workspace: stride 0, raw bytes, bounds off.
__device__ __forceinline__ i32x4 mksrd(const void* p) {
    u64 a = (u64)p;
    i32x4 r;
    r.x = (int)(u32)a;
    r.y = (int)((a >> 32) & 0xFFFFu);   // base hi16, stride=0
    r.z = (int)0xFFFFFFFFu;             // num_records: disable bounds
    r.w = 0x00020000;                   // raw dword access
    return r;
}

// Counted-vmcnt wait + scheduling fence (rule #18: MFMA must not hoist above).
#define WAITV(N) do { asm volatile("s_waitcnt vmcnt(" #N ")" ::: "memory"); \
                      __builtin_amdgcn_sched_barrier(0); } while (0)

// sc0 (L2-resident) ops: legal coherence point is the group's XCD L2.
__device__ __forceinline__ void ld16s(bf16x8& d, i32x4 rs, u32 voff) {
    asm volatile("buffer_load_dwordx4 %0, %1, %2, 0 offen sc0"
                 : "=v"(d) : "v"(voff), "s"(rs));
}
__device__ __forceinline__ void st4s(i32x4 rs, u32 voff, u32 v) {
    asm volatile("buffer_store_dword %0, %1, %2, 0 offen sc0"
                 :: "v"(v), "v"(voff), "s"(rs) : "memory");
}
__device__ __forceinline__ u32 ld4s(i32x4 rs, u32 voff) {
    u32 d;
    asm volatile("buffer_load_dword %0, %1, %2, 0 offen sc0"
                 : "=v"(d) : "v"(voff), "s"(rs) : "memory");
    return d;
}
// fast readiness snapshot: lane p reads fast-flag word p (sc0), ballot >= tgt
__device__ __forceinline__ u32 mkrdy_fast(i32x4 rs, u32 flB, int lane, u32 tgt) {
    u32 v;
    u32 off = flB + (u32)((lane & 31) * 4);
    asm volatile("buffer_load_dword %0, %1, %2, 0 offen sc0\n\t"
                 "s_waitcnt vmcnt(0)"
                 : "=v"(v) : "v"(off), "s"(rs) : "memory");
    unsigned long long b = __ballot(v >= tgt);
    return (u32)b;
}
// safe readiness snapshot: agent-scope flags (always visible, any XCD mapping)
__device__ __forceinline__ u32 mkrdy_safe(const u32* fl, int lane, u32 tgt) {
    u32 v = __hip_atomic_load(fl + (lane & 31), __ATOMIC_RELAXED,
                              __HIP_MEMORY_SCOPE_AGENT);
    unsigned long long b = __ballot(v >= tgt);
    return (u32)b;
}

// ---------------------------------------------------------------------------
// MFMA persistent 2-layer LSTM. 256 blocks (1/CU) x 256 threads (4 waves).
// Round-14 champion (1460 us: sc0 L2 h-ring + A-dedup + lo*lo dropped) with
// ONE change: x is loaded DIRECTLY INTO REGISTERS (5x float2 per thread,
// quad-redundant reads L1-broadcast) at the top of the loop, BEFORE the gate
// — the gate's internal vmcnt(0) polls absorb the load latency. This deletes
// the LDS x-staging pass and its dedicated __syncthreads (3 -> 2 barriers
// per step). xc arithmetic order unchanged -> absmax stays ~1.2e-4.
// Block (ib,ik): 64 batch rows x 8 hidden units (32 gate cols). Wave wv owns
// rows wv*16..+16, ALL 32 gate cols (2 B-tiles) -> no duplicated A-reads.
// Dual-published flags: sc0 fast word + agent safe word (bounded spin then
// fall back) — no hang possible regardless of XCD mapping.
// ---------------------------------------------------------------------------
__global__ __launch_bounds__(256, 1)
void lstm_mfma(const float* __restrict__ x,
               const float* __restrict__ bih0, const float* __restrict__ bhh0,
               const float* __restrict__ bih1, const float* __restrict__ bhh1,
               const float* __restrict__ Wlin, const float* __restrict__ blin,
               char* __restrict__ wsb, float* __restrict__ out)
{
    __shared__ unsigned short lw[61440];   // B-tiles: [6 pl][8 kc][32 n][40 kpad]
    __shared__ float fsh[5184];            // Wx [10][32] | (unused) | CS [2][64][33]
    float* ldsWx = fsh;
    float* CS    = fsh + 960;

    const int tid  = threadIdx.x;
    const int lane = tid & 63;
    const int wv   = __builtin_amdgcn_readfirstlane(tid >> 6);
    const int quad = lane >> 4;
    const int l15  = lane & 15;
    const int ib   = blockIdx.x & 7;
    const int ik   = blockIdx.x >> 3;
    const int rb0  = ib * 64;

    i32x4 rs = mksrd(wsb);

    const unsigned short* wt = (const unsigned short*)(wsb + BOFF_WT);
    const float* gWx = (const float*)(wsb + BOFF_WX);
    const u32 flF  = OB_FLGF + (u32)(ib * 128);               // fast line (sc0)
    const u32* flS = (const u32*)(wsb + OB_FLGS) + ib * 32;   // safe line (agent)
    u32* flSw      = (u32*)(wsb + OB_FLGS) + ib * 32 + ik;

    // ---- one-time: weight B-tiles (this block's 32-col slice) into LDS ----
    #pragma unroll 1
    for (int j = 0; j < 30; ++j) {
        int i16 = tid + j * 256;               // 0..7679 (b128 units)
        int chk = i16 / 160;                   // plane-chunk 0..47
        int wi  = i16 - chk * 160;             // b128 unit within chunk
        size_t src = (size_t)chk * 40960 + (size_t)ik * 1280 + (size_t)wi * 8;
        *(ulonglong2*)(lw + (size_t)chk * 1280 + (size_t)wi * 8) =
            *(const ulonglong2*)(wt + src);
    }
    for (int n = tid; n < 320; n += 256)
        ldsWx[n] = gWx[(n >> 5) * 1024 + ik * 32 + (n & 31)];

    // biases in regs (eltwise mapping: r = tid>>2, unit-pair up = tid&3)
    float b0r[8], b1r[8];
    {
        int up = tid & 3;
        #pragma unroll
        for (int j = 0; j < 8; ++j) {
            int ul = up * 2 + (j >> 2), g = j & 3;
            int gi = g * 256 + ik * 8 + ul;
            b0r[j] = bih0[gi] + bhh0[gi];
            b1r[j] = bih1[gi] + bhh1[gi];
        }
    }
    float c0s[2] = {0.f, 0.f}, c1s[2] = {0.f, 0.f};
    const u32 oaB = (u32)(quad * 1024 + (wv * 16 + l15) * 16); // A-frag byte off
    const bf16x8* bw = (const bf16x8*)lw;
    const float* xrow = x + (size_t)(rb0 + (tid >> 2)) * 2560;  // my batch row
    int safeMode = 0;

    __syncthreads();

    for (int e = 0; e <= TT; ++e) {
        // ---- x[te] direct to registers (issued BEFORE the gate; the gate's
        //      vmcnt(0) polls absorb the latency). 5x float2, 8B-aligned. ----
        float2 xr[5];
        {
            int te = (e < TT) ? e : (TT - 1);
            const float2* p = (const float2*)(xrow + te * 10);
            #pragma unroll
            for (int t = 0; t < 5; ++t) xr[t] = p[t];
        }

        // ---- gate: all 32 producers at flag >= e (per-wave, dual-path) ----
        {
            const u32 tgt = (u32)e;
            u32 rdy;
            if (!safeMode) {
                rdy = mkrdy_fast(rs, flF, lane, tgt);
                int sp = 0;
                while (rdy != 0xFFFFFFFFu && ++sp < 4096)
                    rdy = mkrdy_fast(rs, flF, lane, tgt);
                if (rdy != 0xFFFFFFFFu) safeMode = 1;
            }
            if (safeMode) {
                rdy = mkrdy_safe(flS, lane, tgt);
                while (rdy != 0xFFFFFFFFu) {
                    __builtin_amdgcn_s_sleep(2);
                    rdy = mkrdy_safe(flS, lane, tgt);
                }
            }
            __builtin_amdgcn_sched_barrier(0);
        }
        WAITV(0);   // baseline: manual vmcnt counting starts at 0 (x retired too)

        // ---- gemm: 8 k32-chunks; A sc0 from L2 h-ring, B from LDS ----
        const u32 vo0 = OB_H0HI + (u32)((((e + 1) & 1) * 8 + ib) * 32768);
        const u32 vo1 = OB_H0LO + (u32)((((e + 1) & 1) * 8 + ib) * 32768);
        const u32 vo2 = OB_H1HI + (u32)(((e & 1) * 8 + ib) * 32768);
        const u32 vo3 = OB_H1LO + (u32)(((e & 1) * 8 + ib) * 32768);

        bf16x8 fA[2][4];
        #define ISSUE(b, qc) { const u32 tB = (u32)((qc) * 4096) + oaB;   \
            ld16s(fA[b][0], rs, vo0 + tB);                                \
            ld16s(fA[b][1], rs, vo1 + tB);                                \
            ld16s(fA[b][2], rs, vo2 + tB);                                \
            ld16s(fA[b][3], rs, vo3 + tB); }
        ISSUE(0, 0)
        ISSUE(1, 1)

        // ---- x contribution + bias (VALU work covers first A-load latency) ----
        float xc[8];
        {
            int up = tid & 3;
            #pragma unroll
            for (int j = 0; j < 8; ++j) xc[j] = b0r[j];
            #pragma unroll
            for (int i = 0; i < 10; ++i) {
                float xv = (i & 1) ? xr[i >> 1].y : xr[i >> 1].x;
                #pragma unroll
                for (int j = 0; j < 8; ++j)
                    xc[j] += xv * ldsWx[i * 32 + up * 8 + j];
            }
        }

        f32x4 C0[2], C1[2];
        #pragma unroll
        for (int ct = 0; ct < 2; ++ct) {
            C0[ct] = (f32x4){0.f, 0.f, 0.f, 0.f};
            C1[ct] = (f32x4){0.f, 0.f, 0.f, 0.f};
        }

        #pragma unroll
        for (int q = 0; q < 8; ++q) {
            const int b = q & 1;
            bf16x8 wA[2][2], wB[2][2], wC[2][2];   // [hi/lo][col-tile]
            #pragma unroll
            for (int ct = 0; ct < 2; ++ct) {
                int rb = ct * 16 + l15;
                wA[0][ct] = bw[5 * ((0 * 8 + q) * 32 + rb) + quad];  // hh0 hi
                wA[1][ct] = bw[5 * ((1 * 8 + q) * 32 + rb) + quad];  // hh0 lo
                wB[0][ct] = bw[5 * ((2 * 8 + q) * 32 + rb) + quad];  // ih1 hi
                wB[1][ct] = bw[5 * ((3 * 8 + q) * 32 + rb) + quad];  // ih1 lo
                wC[0][ct] = bw[5 * ((4 * 8 + q) * 32 + rb) + quad];  // hh1 hi
                wC[1][ct] = bw[5 * ((5 * 8 + q) * 32 + rb) + quad];  // hh1 lo
            }
            // 2 chunks x 4 loads in flight; retire the oldest 4 (chunk q)
            if (q < 7) { WAITV(4); } else { WAITV(0); }
            bf16x8 a0h = fA[b][0], a0l = fA[b][1];
            bf16x8 a1h = fA[b][2], a1l = fA[b][3];
            #pragma unroll
            for (int ct = 0; ct < 2; ++ct) {
                // hi*hi + hi*lo + lo*hi (lo*lo dropped: <= 2^-18 relative)
                C0[ct] = __builtin_amdgcn_mfma_f32_16x16x32_bf16(a0h, wA[0][ct], C0[ct], 0, 0, 0);
                C0[ct] = __builtin_amdgcn_mfma_f32_16x16x32_bf16(a0h, wA[1][ct], C0[ct], 0, 0, 0);
                C0[ct] = __builtin_amdgcn_mfma_f32_16x16x32_bf16(a0l, wA[0][ct], C0[ct], 0, 0, 0);
                C1[ct] = __builtin_amdgcn_mfma_f32_16x16x32_bf16(a0h, wB[0][ct], C1[ct], 0, 0, 0);
                C1[ct] = __builtin_amdgcn_mfma_f32_16x16x32_bf16(a0h, wB[1][ct], C1[ct], 0, 0, 0);
                C1[ct] = __builtin_amdgcn_mfma_f32_16x16x32_bf16(a0l, wB[0][ct], C1[ct], 0, 0, 0);
                C1[ct] = __builtin_amdgcn_mfma_f32_16x16x32_bf16(a1h, wC[0][ct], C1[ct], 0, 0, 0);
                C1[ct] = __builtin_amdgcn_mfma_f32_16x16x32_bf16(a1h, wC[1][ct], C1[ct], 0, 0, 0);
                C1[ct] = __builtin_amdgcn_mfma_f32_16x16x32_bf16(a1l, wC[0][ct], C1[ct], 0, 0, 0);
            }
            if (q < 6) ISSUE(b, q + 2)
        }
        #undef ISSUE

        // ---- C/D frags -> scratch (D: col=lane&15, row=quad*4+reg) ----
        #pragma unroll
        for (int ct = 0; ct < 2; ++ct)
            #pragma unroll
            for (int reg = 0; reg < 4; ++reg) {
                int rr = wv * 16 + quad * 4 + reg;
                CS[rr * 33 + ct * 16 + l15]        = C0[ct][reg];
                CS[2112 + rr * 33 + ct * 16 + l15] = C1[ct][reg];
            }
        __syncthreads();

        // ---- eltwise (thread = row x unit-pair); pack + sc0 store into L2 ----
        {
            int r = tid >> 2, up = tid & 3;
            if (e < TT) {
                float h0n[2];
                #pragma unroll
                for (int s = 0; s < 2; ++s) {
                    int c4 = up * 8 + s * 4;
                    float gi = CS[r * 33 + c4 + 0] + xc[s * 4 + 0];
                    float gf = CS[r * 33 + c4 + 1] + xc[s * 4 + 1];
                    float gg = CS[r * 33 + c4 + 2] + xc[s * 4 + 2];
                    float go = CS[r * 33 + c4 + 3] + xc[s * 4 + 3];
                    float cn = sigf(gf) * c0s[s] + sigf(gi) * tanhfast(gg);
                    c0s[s] = cn;
                    h0n[s] = sigf(go) * tanhfast(cn);
                }
                u32 sb = (u32)(((e & 1) * 8 + ib) * 32768 + ik * 1024 + 4 * tid);
                st4s(rs, OB_H0HI + sb, (u32)bhi(h0n[0]) | ((u32)bhi(h0n[1]) << 16));
                st4s(rs, OB_H0LO + sb, (u32)blo(h0n[0]) | ((u32)blo(h0n[1]) << 16));
            }
            if (e > 0) {
                float h1n[2];
                #pragma unroll
                for (int s = 0; s < 2; ++s) {
                    int c4 = up * 8 + s * 4;
                    float gi = CS[2112 + r * 33 + c4 + 0] + b1r[s * 4 + 0];
                    float gf = CS[2112 + r * 33 + c4 + 1] + b1r[s * 4 + 1];
                    float gg = CS[2112 + r * 33 + c4 + 2] + b1r[s * 4 + 2];
                    float go = CS[2112 + r * 33 + c4 + 3] + b1r[s * 4 + 3];
                    float cn = sigf(gf) * c1s[s] + sigf(gi) * tanhfast(gg);
                    c1s[s] = cn;
                    h1n[s] = sigf(go) * tanhfast(cn);
                }
                u32 sb = (u32)((((e + 1) & 1) * 8 + ib) * 32768 + ik * 1024 + 4 * tid);
                st4s(rs, OB_H1HI + sb, (u32)bhi(h1n[0]) | ((u32)bhi(h1n[1]) << 16));
                st4s(rs, OB_H1LO + sb, (u32)blo(h1n[0]) | ((u32)blo(h1n[1]) << 16));
            }
        }
        WAITV(0);          // h stores retired at L2 (coherence point)
        __syncthreads();   // all threads' stores done
        if (tid == 0) {
            st4s(rs, flF + (u32)(ik * 4), (u32)(e + 1));      // fast flag (sc0)
            __hip_atomic_store(flSw, (u32)(e + 1),
                               __ATOMIC_RELAXED, __HIP_MEMORY_SCOPE_AGENT);
        }
    }

    // ---- head: y[b] = h1[255] . Wlin + blin (slot 1, tile layout) ----
    if (ik == 0) {
        {
            const u32 tgt = (u32)(TT + 1);
            u32 rdy;
            if (!safeMode) {
                rdy = mkrdy_fast(rs, flF, lane, tgt);
                int sp = 0;
                while (rdy != 0xFFFFFFFFu && ++sp < 4096)
                    rdy = mkrdy_fast(rs, flF, lane, tgt);
                if (rdy != 0xFFFFFFFFu) safeMode = 1;
            }
            if (safeMode) {
                rdy = mkrdy_safe(flS, lane, tgt);
                while (rdy != 0xFFFFFFFFu) {
                    __builtin_amdgcn_s_sleep(2);
                    rdy = mkrdy_safe(flS, lane, tgt);
                }
            }
            __builtin_amdgcn_sched_barrier(0);
        }
        int r = tid >> 2, q4 = tid & 3;
        const u32 bh_ = OB_H1HI + (u32)((8 + ib) * 32768);
        const u32 bl_ = OB_H1LO + (u32)((8 + ib) * 32768);
        float sacc = 0.f;
        #pragma unroll 1
        for (int kk = 0; kk < 64; kk += 8) {
            u32 hw4[4], lw4[4];
            #pragma unroll
            for (int t = 0; t < 4; ++t) {
                int k = q4 * 64 + kk + 2 * t;
                u32 sa = (u32)(((k >> 3) * 512 + r * 8 + (k & 7)) * 2);
                hw4[t] = ld4s(rs, bh_ + sa);
                lw4[t] = ld4s(rs, bl_ + sa);
            }
            WAITV(0);
            #pragma unroll
            for (int t = 0; t < 4; ++t) {
                int k = q4 * 64 + kk + 2 * t;
                sacc += (bff(hw4[t] & 0xFFFFu) + bff(lw4[t] & 0xFFFFu)) * Wlin[k];
                sacc += (bff(hw4[t] >> 16)     + bff(lw4[t] >> 16))     * Wlin[k + 1];
            }
        }
        sacc += __shfl_down(sacc, 2, 4);
        sacc += __shfl_down(sacc, 1, 4);
        if (q4 == 0) out[rb0 + r] = sacc + blin[0];
    }
}

// ---------------------------------------------------------------------------
extern "C" void kernel_launch(void* const* d_in, const int* in_sizes, int n_in,
                              void* d_out, int out_size, void* d_ws, size_t ws_size,
                              hipStream_t stream) {
    const float* x     = (const float*)d_in[0];
    const float* W_ih0 = (const float*)d_in[1];
    const float* W_hh0 = (const float*)d_in[2];
    const float* b_ih0 = (const float*)d_in[3];
    const float* b_hh0 = (const float*)d_in[4];
    const float* W_ih1 = (const float*)d_in[5];
    const float* W_hh1 = (const float*)d_in[6];
    const float* b_ih1 = (const float*)d_in[7];
    const float* b_hh1 = (const float*)d_in[8];
    const float* W_lin = (const float*)d_in[9];
    const float* b_lin = (const float*)d_in[10];
    float* out = (float*)d_out;
    char* wsb  = (char*)d_ws;

    // zero h ring planes + flag region (ws re-poisoned before every timed launch)
    hipMemsetAsync(wsb + BOFF_H0HI, 0, 4 * 524288 + 131584, stream);

    split_w<<<3072, 256, 0, stream>>>(W_hh0, W_ih1, W_hh1,
                                      (unsigned short*)(wsb + BOFF_WT));
    transpose_gi<<<40, 256, 0, stream>>>(W_ih0, (float*)(wsb + BOFF_WX), 10);

    lstm_mfma<<<256, 256, 0, stream>>>(x, b_ih0, b_hh0, b_ih1, b_hh1,
                                       W_lin, b_lin, wsb, out);
}

// Round 16
// 1467.981 us; speedup vs baseline: 1.0259x; 1.0259x over previous
//
#include <hip/hip_runtime.h>
#include <math.h>

typedef unsigned int u32;
typedef unsigned long long u64;
typedef __attribute__((ext_vector_type(8))) short bf16x8;   // 8 bf16 = 4 VGPR
typedef __attribute__((ext_vector_type(4))) float f32x4;
typedef __attribute__((ext_vector_type(4))) int i32x4;

#define TT 256

// ---- ws byte offsets ----
#define BOFF_WT   0ULL          // bf16 [3 mat][2 pl][8 kc][1024 n][40 kpad] = 3,932,160 B
#define BOFF_WX   3932160ULL    // fp32 [10][1024] = 40,960 B
#define BOFF_H0HI 3973120ULL    // bf16 [2 slot][8 ib][32 ik][64 r][8 u] = 524,288 B each
#define BOFF_H0LO 4497408ULL
#define BOFF_H1HI 5021696ULL
#define BOFF_H1LO 5545984ULL
#define BOFF_FLG  6070272ULL    // flag region (fast sc0 lines + safe agent lines)

#define OB_H0HI 3973120u
#define OB_H0LO 4497408u
#define OB_H1HI 5021696u
#define OB_H1LO 5545984u
// fast flags (sc0, L2-resident): one 128B line per ib group, 32 u32 words
#define OB_FLGF 6070272u
// safe flags (agent scope): separate lines, +4096B
#define OB_FLGS 6074368u

// ---------------------------------------------------------------------------
// W [1024][K] row-major -> A [K][1024] gate-interleaved fp32 (for x-gemm)
__global__ void transpose_gi(const float* __restrict__ W, float* __restrict__ A, int K) {
    int idx = blockIdx.x * 256 + threadIdx.x;
    if (idx < K * 1024) {
        int kk = idx >> 10, r = idx & 1023, k = r >> 2, g = r & 3;
        A[idx] = W[(g * 256 + k) * K + kk];
    }
}

// Split fp32 weights into hi/lo bf16 planes, MFMA B-tile layout:
// wt[((mt*2+pl)*8 + kc)*1024 + n][40] , n = gate-col (u*4+g), k within chunk 0..31
__global__ void split_w(const float* __restrict__ W0, const float* __restrict__ W1,
                        const float* __restrict__ W2, unsigned short* __restrict__ wt) {
    int idx = blockIdx.x * 256 + threadIdx.x;      // 786432 total
    int k32 = idx & 31;
    int n   = (idx >> 5) & 1023;
    int kc  = (idx >> 15) & 7;
    int mt  = idx >> 18;
    const float* W = (mt == 0) ? W0 : (mt == 1) ? W1 : W2;
    int ug = n >> 2, g = n & 3, k = kc * 32 + k32;
    float v = W[(g * 256 + ug) * 256 + k];
    u32 b = __float_as_uint(v);
    unsigned short hi = (unsigned short)(b >> 16);               // truncated hi
    float lo = v - __uint_as_float(b & 0xFFFF0000u);             // exact residual
    u32 lb = __float_as_uint(lo);
    unsigned short los = (unsigned short)((lb + 0x7FFFu + ((lb >> 16) & 1u)) >> 16);
    wt[((size_t)((mt * 2 + 0) * 8 + kc) * 1024 + n) * 40 + k32] = hi;
    wt[((size_t)((mt * 2 + 1) * 8 + kc) * 1024 + n) * 40 + k32] = los;
}

__device__ __forceinline__ float sigf(float x)     { return 1.0f / (1.0f + __expf(-x)); }
__device__ __forceinline__ float tanhfast(float x) { return 1.0f - 2.0f / (__expf(2.0f * x) + 1.0f); }

__device__ __forceinline__ unsigned short bhi(float v) {
    return (unsigned short)(__float_as_uint(v) >> 16);
}
__device__ __forceinline__ unsigned short blo(float v) {
    float lo = v - __uint_as_float(__float_as_uint(v) & 0xFFFF0000u);
    u32 lb = __float_as_uint(lo);
    return (unsigned short)((lb + 0x7FFFu + ((lb >> 16) & 1u)) >> 16);
}
__device__ __forceinline__ float bff(u32 us) { return __uint_as_float(us << 16); }

// SRD over the whole workspace: stride 0, raw bytes, bounds off.
__device__ __forceinline__ i32x4 mksrd(const void* p) {
    u64 a = (u64)p;
    i32x4 r;
    r.x = (int)(u32)a;
    r.y = (int)((a >> 32) & 0xFFFFu);   // base hi16, stride=0
    r.z = (int)0xFFFFFFFFu;             // num_records: disable bounds
    r.w = 0x00020000;                   // raw dword access
    return r;
}

// Counted-vmcnt wait + scheduling fence (rule #18: MFMA must not hoist above).
#define WAITV(N) do { asm volatile("s_waitcnt vmcnt(" #N ")" ::: "memory"); \
                      __builtin_amdgcn_sched_barrier(0); } while (0)

// sc0 (L2-resident) ops: legal coherence point is the group's XCD L2.
__device__ __forceinline__ void ld16s(bf16x8& d, i32x4 rs, u32 voff) {
    asm volatile("buffer_load_dwordx4 %0, %1, %2, 0 offen sc0"
                 : "=v"(d) : "v"(voff), "s"(rs));
}
__device__ __forceinline__ void st4s(i32x4 rs, u32 voff, u32 v) {
    asm volatile("buffer_store_dword %0, %1, %2, 0 offen sc0"
                 :: "v"(v), "v"(voff), "s"(rs) : "memory");
}
__device__ __forceinline__ u32 ld4s(i32x4 rs, u32 voff) {
    u32 d;
    asm volatile("buffer_load_dword %0, %1, %2, 0 offen sc0"
                 : "=v"(d) : "v"(voff), "s"(rs) : "memory");
    return d;
}
// fast readiness snapshot: lane p reads fast-flag word p (sc0), ballot >= tgt
__device__ __forceinline__ u32 mkrdy_fast(i32x4 rs, u32 flB, int lane, u32 tgt) {
    u32 v;
    u32 off = flB + (u32)((lane & 31) * 4);
    asm volatile("buffer_load_dword %0, %1, %2, 0 offen sc0\n\t"
                 "s_waitcnt vmcnt(0)"
                 : "=v"(v) : "v"(off), "s"(rs) : "memory");
    unsigned long long b = __ballot(v >= tgt);
    return (u32)b;
}
// safe readiness snapshot: agent-scope flags (always visible, any XCD mapping)
__device__ __forceinline__ u32 mkrdy_safe(const u32* fl, int lane, u32 tgt) {
    u32 v = __hip_atomic_load(fl + (lane & 31), __ATOMIC_RELAXED,
                              __HIP_MEMORY_SCOPE_AGENT);
    unsigned long long b = __ballot(v >= tgt);
    return (u32)b;
}

// ---------------------------------------------------------------------------
// MFMA persistent 2-layer LSTM. 256 blocks (1/CU) x 256 threads (4 waves).
// Round-14 champion (1460 us: sc0 L2 h-ring + A-dedup + lo*lo dropped +
// LDS x-staging) with ONE change: C1 is SPLIT into two accumulators
// (C1a = ih1 terms, C1b = hh1 terms, summed at the CS write) — the longest
// dependent-MFMA chain drops 6 -> 3 per chunk (48 -> 24 across the step),
// halving exposed accumulate latency at 1 wave/SIMD. Pure reordering of a
// float sum; absmax stays ~1e-4.
// Block (ib,ik): 64 batch rows x 8 hidden units (32 gate cols). Wave wv owns
// rows wv*16..+16, ALL 32 gate cols (2 B-tiles) -> no duplicated A-reads.
// Dual-published flags: sc0 fast word + agent safe word (bounded spin then
// fall back) — no hang possible regardless of XCD mapping.
// ---------------------------------------------------------------------------
__global__ __launch_bounds__(256, 1)
void lstm_mfma(const float* __restrict__ x,
               const float* __restrict__ bih0, const float* __restrict__ bhh0,
               const float* __restrict__ bih1, const float* __restrict__ bhh1,
               const float* __restrict__ Wlin, const float* __restrict__ blin,
               char* __restrict__ wsb, float* __restrict__ out)
{
    __shared__ unsigned short lw[61440];   // B-tiles: [6 pl][8 kc][32 n][40 kpad]
    __shared__ float fsh[5184];            // Wx [10][32] | xs [10][64] | CS [2][64][33]
    float* ldsWx = fsh;
    float* xs    = fsh + 320;
    float* CS    = fsh + 960;

    const int tid  = threadIdx.x;
    const int lane = tid & 63;
    const int wv   = __builtin_amdgcn_readfirstlane(tid >> 6);
    const int quad = lane >> 4;
    const int l15  = lane & 15;
    const int ib   = blockIdx.x & 7;
    const int ik   = blockIdx.x >> 3;
    const int rb0  = ib * 64;

    i32x4 rs = mksrd(wsb);

    const unsigned short* wt = (const unsigned short*)(wsb + BOFF_WT);
    const float* gWx = (const float*)(wsb + BOFF_WX);
    const u32 flF  = OB_FLGF + (u32)(ib * 128);               // fast line (sc0)
    const u32* flS = (const u32*)(wsb + OB_FLGS) + ib * 32;   // safe line (agent)
    u32* flSw      = (u32*)(wsb + OB_FLGS) + ib * 32 + ik;

    // ---- one-time: weight B-tiles (this block's 32-col slice) into LDS ----
    #pragma unroll 1
    for (int j = 0; j < 30; ++j) {
        int i16 = tid + j * 256;               // 0..7679 (b128 units)
        int chk = i16 / 160;                   // plane-chunk 0..47
        int wi  = i16 - chk * 160;             // b128 unit within chunk
        size_t src = (size_t)chk * 40960 + (size_t)ik * 1280 + (size_t)wi * 8;
        *(ulonglong2*)(lw + (size_t)chk * 1280 + (size_t)wi * 8) =
            *(const ulonglong2*)(wt + src);
    }
    for (int n = tid; n < 320; n += 256)
        ldsWx[n] = gWx[(n >> 5) * 1024 + ik * 32 + (n & 31)];

    // biases in regs (eltwise mapping: r = tid>>2, unit-pair up = tid&3)
    float b0r[8], b1r[8];
    {
        int up = tid & 3;
        #pragma unroll
        for (int j = 0; j < 8; ++j) {
            int ul = up * 2 + (j >> 2), g = j & 3;
            int gi = g * 256 + ik * 8 + ul;
            b0r[j] = bih0[gi] + bhh0[gi];
            b1r[j] = bih1[gi] + bhh1[gi];
        }
    }
    float c0s[2] = {0.f, 0.f}, c1s[2] = {0.f, 0.f};
    const u32 oaB = (u32)(quad * 1024 + (wv * 16 + l15) * 16); // A-frag byte off
    const bf16x8* bw = (const bf16x8*)lw;
    int safeMode = 0;

    __syncthreads();

    for (int e = 0; e <= TT; ++e) {
        // ---- stage x[te] ----
        {
            int te = (e < TT) ? e : (TT - 1);
            #pragma unroll
            for (int rr = 0; rr < 2; ++rr) {
                int idx = tid + rr * 256;
                if (idx < 320) {
                    int r = idx / 5, j2 = idx - r * 5;
                    float2 v = *(const float2*)(x + (size_t)(rb0 + r) * 2560 + te * 10 + 2 * j2);
                    xs[(2 * j2) * 64 + r]     = v.x;
                    xs[(2 * j2 + 1) * 64 + r] = v.y;
                }
            }
        }
        __syncthreads();   // xs visible

        // ---- gate: all 32 producers at flag >= e (per-wave, dual-path) ----
        {
            const u32 tgt = (u32)e;
            u32 rdy;
            if (!safeMode) {
                rdy = mkrdy_fast(rs, flF, lane, tgt);
                int sp = 0;
                while (rdy != 0xFFFFFFFFu && ++sp < 4096)
                    rdy = mkrdy_fast(rs, flF, lane, tgt);
                if (rdy != 0xFFFFFFFFu) safeMode = 1;
            }
            if (safeMode) {
                rdy = mkrdy_safe(flS, lane, tgt);
                while (rdy != 0xFFFFFFFFu) {
                    __builtin_amdgcn_s_sleep(2);
                    rdy = mkrdy_safe(flS, lane, tgt);
                }
            }
            __builtin_amdgcn_sched_barrier(0);
        }
        WAITV(0);   // baseline: manual vmcnt counting starts at 0

        // ---- gemm: 8 k32-chunks; A sc0 from L2 h-ring, B from LDS ----
        const u32 vo0 = OB_H0HI + (u32)((((e + 1) & 1) * 8 + ib) * 32768);
        const u32 vo1 = OB_H0LO + (u32)((((e + 1) & 1) * 8 + ib) * 32768);
        const u32 vo2 = OB_H1HI + (u32)(((e & 1) * 8 + ib) * 32768);
        const u32 vo3 = OB_H1LO + (u32)(((e & 1) * 8 + ib) * 32768);

        bf16x8 fA[2][4];
        #define ISSUE(b, qc) { const u32 tB = (u32)((qc) * 4096) + oaB;   \
            ld16s(fA[b][0], rs, vo0 + tB);                                \
            ld16s(fA[b][1], rs, vo1 + tB);                                \
            ld16s(fA[b][2], rs, vo2 + tB);                                \
            ld16s(fA[b][3], rs, vo3 + tB); }
        ISSUE(0, 0)
        ISSUE(1, 1)

        // ---- x contribution + bias (VALU work covers first A-load latency) ----
        float xc[8];
        {
            int r = tid >> 2, up = tid & 3;
            #pragma unroll
            for (int j = 0; j < 8; ++j) xc[j] = b0r[j];
            #pragma unroll
            for (int i = 0; i < 10; ++i) {
                float xv = xs[i * 64 + r];
                #pragma unroll
                for (int j = 0; j < 8; ++j)
                    xc[j] += xv * ldsWx[i * 32 + up * 8 + j];
            }
        }

        f32x4 C0[2], C1a[2], C1b[2];
        #pragma unroll
        for (int ct = 0; ct < 2; ++ct) {
            C0[ct]  = (f32x4){0.f, 0.f, 0.f, 0.f};
            C1a[ct] = (f32x4){0.f, 0.f, 0.f, 0.f};
            C1b[ct] = (f32x4){0.f, 0.f, 0.f, 0.f};
        }

        #pragma unroll
        for (int q = 0; q < 8; ++q) {
            const int b = q & 1;
            bf16x8 wA[2][2], wB[2][2], wC[2][2];   // [hi/lo][col-tile]
            #pragma unroll
            for (int ct = 0; ct < 2; ++ct) {
                int rb = ct * 16 + l15;
                wA[0][ct] = bw[5 * ((0 * 8 + q) * 32 + rb) + quad];  // hh0 hi
                wA[1][ct] = bw[5 * ((1 * 8 + q) * 32 + rb) + quad];  // hh0 lo
                wB[0][ct] = bw[5 * ((2 * 8 + q) * 32 + rb) + quad];  // ih1 hi
                wB[1][ct] = bw[5 * ((3 * 8 + q) * 32 + rb) + quad];  // ih1 lo
                wC[0][ct] = bw[5 * ((4 * 8 + q) * 32 + rb) + quad];  // hh1 hi
                wC[1][ct] = bw[5 * ((5 * 8 + q) * 32 + rb) + quad];  // hh1 lo
            }
            // 2 chunks x 4 loads in flight; retire the oldest 4 (chunk q)
            if (q < 7) { WAITV(4); } else { WAITV(0); }
            bf16x8 a0h = fA[b][0], a0l = fA[b][1];
            bf16x8 a1h = fA[b][2], a1l = fA[b][3];
            #pragma unroll
            for (int ct = 0; ct < 2; ++ct) {
                // hi*hi + hi*lo + lo*hi (lo*lo dropped: <= 2^-18 relative);
                // C1 split into ih1 (C1a) and hh1 (C1b) accumulators —
                // six independent 3-deep chains per chunk.
                C0[ct]  = __builtin_amdgcn_mfma_f32_16x16x32_bf16(a0h, wA[0][ct], C0[ct],  0, 0, 0);
                C0[ct]  = __builtin_amdgcn_mfma_f32_16x16x32_bf16(a0h, wA[1][ct], C0[ct],  0, 0, 0);
                C0[ct]  = __builtin_amdgcn_mfma_f32_16x16x32_bf16(a0l, wA[0][ct], C0[ct],  0, 0, 0);
                C1a[ct] = __builtin_amdgcn_mfma_f32_16x16x32_bf16(a0h, wB[0][ct], C1a[ct], 0, 0, 0);
                C1a[ct] = __builtin_amdgcn_mfma_f32_16x16x32_bf16(a0h, wB[1][ct], C1a[ct], 0, 0, 0);
                C1a[ct] = __builtin_amdgcn_mfma_f32_16x16x32_bf16(a0l, wB[0][ct], C1a[ct], 0, 0, 0);
                C1b[ct] = __builtin_amdgcn_mfma_f32_16x16x32_bf16(a1h, wC[0][ct], C1b[ct], 0, 0, 0);
                C1b[ct] = __builtin_amdgcn_mfma_f32_16x16x32_bf16(a1h, wC[1][ct], C1b[ct], 0, 0, 0);
                C1b[ct] = __builtin_amdgcn_mfma_f32_16x16x32_bf16(a1l, wC[0][ct], C1b[ct], 0, 0, 0);
            }
            if (q < 6) ISSUE(b, q + 2)
        }
        #undef ISSUE

        // ---- C/D frags -> scratch (D: col=lane&15, row=quad*4+reg) ----
        #pragma unroll
        for (int ct = 0; ct < 2; ++ct)
            #pragma unroll
            for (int reg = 0; reg < 4; ++reg) {
                int rr = wv * 16 + quad * 4 + reg;
                CS[rr * 33 + ct * 16 + l15]        = C0[ct][reg];
                CS[2112 + rr * 33 + ct * 16 + l15] = C1a[ct][reg] + C1b[ct][reg];
            }
        __syncthreads();

        // ---- eltwise (thread = row x unit-pair); pack + sc0 store into L2 ----
        {
            int r = tid >> 2, up = tid & 3;
            if (e < TT) {
                float h0n[2];
                #pragma unroll
                for (int s = 0; s < 2; ++s) {
                    int c4 = up * 8 + s * 4;
                    float gi = CS[r * 33 + c4 + 0] + xc[s * 4 + 0];
                    float gf = CS[r * 33 + c4 + 1] + xc[s * 4 + 1];
                    float gg = CS[r * 33 + c4 + 2] + xc[s * 4 + 2];
                    float go = CS[r * 33 + c4 + 3] + xc[s * 4 + 3];
                    float cn = sigf(gf) * c0s[s] + sigf(gi) * tanhfast(gg);
                    c0s[s] = cn;
                    h0n[s] = sigf(go) * tanhfast(cn);
                }
                u32 sb = (u32)(((e & 1) * 8 + ib) * 32768 + ik * 1024 + 4 * tid);
                st4s(rs, OB_H0HI + sb, (u32)bhi(h0n[0]) | ((u32)bhi(h0n[1]) << 16));
                st4s(rs, OB_H0LO + sb, (u32)blo(h0n[0]) | ((u32)blo(h0n[1]) << 16));
            }
            if (e > 0) {
                float h1n[2];
                #pragma unroll
                for (int s = 0; s < 2; ++s) {
                    int c4 = up * 8 + s * 4;
                    float gi = CS[2112 + r * 33 + c4 + 0] + b1r[s * 4 + 0];
                    float gf = CS[2112 + r * 33 + c4 + 1] + b1r[s * 4 + 1];
                    float gg = CS[2112 + r * 33 + c4 + 2] + b1r[s * 4 + 2];
                    float go = CS[2112 + r * 33 + c4 + 3] + b1r[s * 4 + 3];
                    float cn = sigf(gf) * c1s[s] + sigf(gi) * tanhfast(gg);
                    c1s[s] = cn;
                    h1n[s] = sigf(go) * tanhfast(cn);
                }
                u32 sb = (u32)((((e + 1) & 1) * 8 + ib) * 32768 + ik * 1024 + 4 * tid);
                st4s(rs, OB_H1HI + sb, (u32)bhi(h1n[0]) | ((u32)bhi(h1n[1]) << 16));
                st4s(rs, OB_H1LO + sb, (u32)blo(h1n[0]) | ((u32)blo(h1n[1]) << 16));
            }
        }
        WAITV(0);          // h stores retired at L2 (coherence point)
        __syncthreads();   // all threads' stores done
        if (tid == 0) {
            st4s(rs, flF + (u32)(ik * 4), (u32)(e + 1));      // fast flag (sc0)
            __hip_atomic_store(flSw, (u32)(e + 1),
                               __ATOMIC_RELAXED, __HIP_MEMORY_SCOPE_AGENT);
        }
    }

    // ---- head: y[b] = h1[255] . Wlin + blin (slot 1, tile layout) ----
    if (ik == 0) {
        {
            const u32 tgt = (u32)(TT + 1);
            u32 rdy;
            if (!safeMode) {
                rdy = mkrdy_fast(rs, flF, lane, tgt);
                int sp = 0;
                while (rdy != 0xFFFFFFFFu && ++sp < 4096)
                    rdy = mkrdy_fast(rs, flF, lane, tgt);
                if (rdy != 0xFFFFFFFFu) safeMode = 1;
            }
            if (safeMode) {
                rdy = mkrdy_safe(flS, lane, tgt);
                while (rdy != 0xFFFFFFFFu) {
                    __builtin_amdgcn_s_sleep(2);
                    rdy = mkrdy_safe(flS, lane, tgt);
                }
            }
            __builtin_amdgcn_sched_barrier(0);
        }
        int r = tid >> 2, q4 = tid & 3;
        const u32 bh_ = OB_H1HI + (u32)((8 + ib) * 32768);
        const u32 bl_ = OB_H1LO + (u32)((8 + ib) * 32768);
        float sacc = 0.f;
        #pragma unroll 1
        for (int kk = 0; kk < 64; kk += 8) {
            u32 hw4[4], lw4[4];
            #pragma unroll
            for (int t = 0; t < 4; ++t) {
                int k = q4 * 64 + kk + 2 * t;
                u32 sa = (u32)(((k >> 3) * 512 + r * 8 + (k & 7)) * 2);
                hw4[t] = ld4s(rs, bh_ + sa);
                lw4[t] = ld4s(rs, bl_ + sa);
            }
            WAITV(0);
            #pragma unroll
            for (int t = 0; t < 4; ++t) {
                int k = q4 * 64 + kk + 2 * t;
                sacc += (bff(hw4[t] & 0xFFFFu) + bff(lw4[t] & 0xFFFFu)) * Wlin[k];
                sacc += (bff(hw4[t] >> 16)     + bff(lw4[t] >> 16))     * Wlin[k + 1];
            }
        }
        sacc += __shfl_down(sacc, 2, 4);
        sacc += __shfl_down(sacc, 1, 4);
        if (q4 == 0) out[rb0 + r] = sacc + blin[0];
    }
}

// ---------------------------------------------------------------------------
extern "C" void kernel_launch(void* const* d_in, const int* in_sizes, int n_in,
                              void* d_out, int out_size, void* d_ws, size_t ws_size,
                              hipStream_t stream) {
    const float* x     = (const float*)d_in[0];
    const float* W_ih0 = (const float*)d_in[1];
    const float* W_hh0 = (const float*)d_in[2];
    const float* b_ih0 = (const float*)d_in[3];
    const float* b_hh0 = (const float*)d_in[4];
    const float* W_ih1 = (const float*)d_in[5];
    const float* W_hh1 = (const float*)d_in[6];
    const float* b_ih1 = (const float*)d_in[7];
    const float* b_hh1 = (const float*)d_in[8];
    const float* W_lin = (const float*)d_in[9];
    const float* b_lin = (const float*)d_in[10];
    float* out = (float*)d_out;
    char* wsb  = (char*)d_ws;

    // zero h ring planes + flag region (ws re-poisoned before every timed launch)
    hipMemsetAsync(wsb + BOFF_H0HI, 0, 4 * 524288 + 131584, stream);

    split_w<<<3072, 256, 0, stream>>>(W_hh0, W_ih1, W_hh1,
                                      (unsigned short*)(wsb + BOFF_WT));
    transpose_gi<<<40, 256, 0, stream>>>(W_ih0, (float*)(wsb + BOFF_WX), 10);

    lstm_mfma<<<256, 256, 0, stream>>>(x, b_ih0, b_hh0, b_ih1, b_hh1,
                                       W_lin, b_lin, wsb, out);
}

// Round 18
// 1459.459 us; speedup vs baseline: 1.0319x; 1.0058x over previous
//
#include <hip/hip_runtime.h>
#include <math.h>

typedef unsigned int u32;
typedef unsigned long long u64;
typedef __attribute__((ext_vector_type(8))) short bf16x8;   // 8 bf16 = 4 VGPR
typedef __attribute__((ext_vector_type(4))) float f32x4;
typedef __attribute__((ext_vector_type(4))) int i32x4;

#define TT 256

// ---- ws byte offsets ----
#define BOFF_WT   0ULL          // bf16 [3 mat][2 pl][8 kc][1024 n][40 kpad] = 3,932,160 B
#define BOFF_WX   3932160ULL    // fp32 [10][1024] = 40,960 B
#define BOFF_H0HI 3973120ULL    // bf16 [2 slot][8 ib][32 ik][64 r][8 u] = 524,288 B each
#define BOFF_H0LO 4497408ULL
#define BOFF_H1HI 5021696ULL
#define BOFF_H1LO 5545984ULL
#define BOFF_FLG  6070272ULL    // flag region (fast sc0 lines + safe agent lines)

#define OB_H0HI 3973120u
#define OB_H0LO 4497408u
#define OB_H1HI 5021696u
#define OB_H1LO 5545984u
// fast flags (sc0, L2-resident): one 128B line per ib group, 32 u32 words
#define OB_FLGF 6070272u
// safe flags (agent scope): separate lines, +4096B
#define OB_FLGS 6074368u

// ---------------------------------------------------------------------------
// W [1024][K] row-major -> A [K][1024] gate-interleaved fp32 (for x-gemm)
__global__ void transpose_gi(const float* __restrict__ W, float* __restrict__ A, int K) {
    int idx = blockIdx.x * 256 + threadIdx.x;
    if (idx < K * 1024) {
        int kk = idx >> 10, r = idx & 1023, k = r >> 2, g = r & 3;
        A[idx] = W[(g * 256 + k) * K + kk];
    }
}

// Split fp32 weights into hi/lo bf16 planes, MFMA B-tile layout:
// wt[((mt*2+pl)*8 + kc)*1024 + n][40] , n = gate-col (u*4+g), k within chunk 0..31
__global__ void split_w(const float* __restrict__ W0, const float* __restrict__ W1,
                        const float* __restrict__ W2, unsigned short* __restrict__ wt) {
    int idx = blockIdx.x * 256 + threadIdx.x;      // 786432 total
    int k32 = idx & 31;
    int n   = (idx >> 5) & 1023;
    int kc  = (idx >> 15) & 7;
    int mt  = idx >> 18;
    const float* W = (mt == 0) ? W0 : (mt == 1) ? W1 : W2;
    int ug = n >> 2, g = n & 3, k = kc * 32 + k32;
    float v = W[(g * 256 + ug) * 256 + k];
    u32 b = __float_as_uint(v);
    unsigned short hi = (unsigned short)(b >> 16);               // truncated hi
    float lo = v - __uint_as_float(b & 0xFFFF0000u);             // exact residual
    u32 lb = __float_as_uint(lo);
    unsigned short los = (unsigned short)((lb + 0x7FFFu + ((lb >> 16) & 1u)) >> 16);
    wt[((size_t)((mt * 2 + 0) * 8 + kc) * 1024 + n) * 40 + k32] = hi;
    wt[((size_t)((mt * 2 + 1) * 8 + kc) * 1024 + n) * 40 + k32] = los;
}

__device__ __forceinline__ float sigf(float x)     { return 1.0f / (1.0f + __expf(-x)); }
__device__ __forceinline__ float tanhfast(float x) { return 1.0f - 2.0f / (__expf(2.0f * x) + 1.0f); }

__device__ __forceinline__ unsigned short bhi(float v) {
    return (unsigned short)(__float_as_uint(v) >> 16);
}
__device__ __forceinline__ unsigned short blo(float v) {
    float lo = v - __uint_as_float(__float_as_uint(v) & 0xFFFF0000u);
    u32 lb = __float_as_uint(lo);
    return (unsigned short)((lb + 0x7FFFu + ((lb >> 16) & 1u)) >> 16);
}
__device__ __forceinline__ float bff(u32 us) { return __uint_as_float(us << 16); }

// SRD over the whole workspace: stride 0, raw bytes, bounds off.
__device__ __forceinline__ i32x4 mksrd(const void* p) {
    u64 a = (u64)p;
    i32x4 r;
    r.x = (int)(u32)a;
    r.y = (int)((a >> 32) & 0xFFFFu);   // base hi16, stride=0
    r.z = (int)0xFFFFFFFFu;             // num_records: disable bounds
    r.w = 0x00020000;                   // raw dword access
    return r;
}

// Counted-vmcnt wait + scheduling fence (rule #18: MFMA must not hoist above).
#define WAITV(N) do { asm volatile("s_waitcnt vmcnt(" #N ")" ::: "memory"); \
                      __builtin_amdgcn_sched_barrier(0); } while (0)

// sc0 (L2-resident) ops: legal coherence point is the group's XCD L2.
__device__ __forceinline__ void ld16s(bf16x8& d, i32x4 rs, u32 voff) {
    asm volatile("buffer_load_dwordx4 %0, %1, %2, 0 offen sc0"
                 : "=v"(d) : "v"(voff), "s"(rs));
}
__device__ __forceinline__ void st4s(i32x4 rs, u32 voff, u32 v) {
    asm volatile("buffer_store_dword %0, %1, %2, 0 offen sc0"
                 :: "v"(v), "v"(voff), "s"(rs) : "memory");
}
__device__ __forceinline__ u32 ld4s(i32x4 rs, u32 voff) {
    u32 d;
    asm volatile("buffer_load_dword %0, %1, %2, 0 offen sc0"
                 : "=v"(d) : "v"(voff), "s"(rs) : "memory");
    return d;
}
// fast readiness snapshot: lane p reads fast-flag word p (sc0), ballot >= tgt
__device__ __forceinline__ u32 mkrdy_fast(i32x4 rs, u32 flB, int lane, u32 tgt) {
    u32 v;
    u32 off = flB + (u32)((lane & 31) * 4);
    asm volatile("buffer_load_dword %0, %1, %2, 0 offen sc0\n\t"
                 "s_waitcnt vmcnt(0)"
                 : "=v"(v) : "v"(off), "s"(rs) : "memory");
    unsigned long long b = __ballot(v >= tgt);
    return (u32)b;
}
// safe readiness snapshot: agent-scope flags (always visible, any XCD mapping)
__device__ __forceinline__ u32 mkrdy_safe(const u32* fl, int lane, u32 tgt) {
    u32 v = __hip_atomic_load(fl + (lane & 31), __ATOMIC_RELAXED,
                              __HIP_MEMORY_SCOPE_AGENT);
    unsigned long long b = __ballot(v >= tgt);
    return (u32)b;
}

// ---------------------------------------------------------------------------
// MFMA persistent 2-layer LSTM. 256 blocks (1/CU) x 256 threads (4 waves).
// CHAMPION STRUCTURE (round 14, verified 1460 us):
//  - h ring + flags L2-resident via sc0 buffer ops (ib = blockIdx%8 groups
//    XCD-uniform under round-robin dispatch; L2 is the coherence point).
//  - Wave wv owns rows wv*16..+16 x ALL 32 gate cols -> no duplicated
//    A-reads between waves (halves group L2 multicast traffic).
//  - hi/lo bf16 split with lo*lo dropped (<= 2^-18 relative): 9 MFMAs per
//    chunk per wave; absmax ~1.2e-4.
//  - 2-deep chunk pipeline with counted vmcnt(4); LDS B-tiles; LDS x-staging.
// Dual-published flags: sc0 fast word + agent safe word (bounded spin then
// fall back) — no hang possible regardless of XCD mapping.
// Remaining step time is structural: 32-way L2 h-multicast BW + the serial
// produce->publish->consume chain + max-of-32 straggle, x257 rounds.
// ---------------------------------------------------------------------------
__global__ __launch_bounds__(256, 1)
void lstm_mfma(const float* __restrict__ x,
               const float* __restrict__ bih0, const float* __restrict__ bhh0,
               const float* __restrict__ bih1, const float* __restrict__ bhh1,
               const float* __restrict__ Wlin, const float* __restrict__ blin,
               char* __restrict__ wsb, float* __restrict__ out)
{
    __shared__ unsigned short lw[61440];   // B-tiles: [6 pl][8 kc][32 n][40 kpad]
    __shared__ float fsh[5184];            // Wx [10][32] | xs [10][64] | CS [2][64][33]
    float* ldsWx = fsh;
    float* xs    = fsh + 320;
    float* CS    = fsh + 960;

    const int tid  = threadIdx.x;
    const int lane = tid & 63;
    const int wv   = __builtin_amdgcn_readfirstlane(tid >> 6);
    const int quad = lane >> 4;
    const int l15  = lane & 15;
    const int ib   = blockIdx.x & 7;
    const int ik   = blockIdx.x >> 3;
    const int rb0  = ib * 64;

    i32x4 rs = mksrd(wsb);

    const unsigned short* wt = (const unsigned short*)(wsb + BOFF_WT);
    const float* gWx = (const float*)(wsb + BOFF_WX);
    const u32 flF  = OB_FLGF + (u32)(ib * 128);               // fast line (sc0)
    const u32* flS = (const u32*)(wsb + OB_FLGS) + ib * 32;   // safe line (agent)
    u32* flSw      = (u32*)(wsb + OB_FLGS) + ib * 32 + ik;

    // ---- one-time: weight B-tiles (this block's 32-col slice) into LDS ----
    #pragma unroll 1
    for (int j = 0; j < 30; ++j) {
        int i16 = tid + j * 256;               // 0..7679 (b128 units)
        int chk = i16 / 160;                   // plane-chunk 0..47
        int wi  = i16 - chk * 160;             // b128 unit within chunk
        size_t src = (size_t)chk * 40960 + (size_t)ik * 1280 + (size_t)wi * 8;
        *(ulonglong2*)(lw + (size_t)chk * 1280 + (size_t)wi * 8) =
            *(const ulonglong2*)(wt + src);
    }
    for (int n = tid; n < 320; n += 256)
        ldsWx[n] = gWx[(n >> 5) * 1024 + ik * 32 + (n & 31)];

    // biases in regs (eltwise mapping: r = tid>>2, unit-pair up = tid&3)
    float b0r[8], b1r[8];
    {
        int up = tid & 3;
        #pragma unroll
        for (int j = 0; j < 8; ++j) {
            int ul = up * 2 + (j >> 2), g = j & 3;
            int gi = g * 256 + ik * 8 + ul;
            b0r[j] = bih0[gi] + bhh0[gi];
            b1r[j] = bih1[gi] + bhh1[gi];
        }
    }
    float c0s[2] = {0.f, 0.f}, c1s[2] = {0.f, 0.f};
    const u32 oaB = (u32)(quad * 1024 + (wv * 16 + l15) * 16); // A-frag byte off
    const bf16x8* bw = (const bf16x8*)lw;
    int safeMode = 0;

    __syncthreads();

    for (int e = 0; e <= TT; ++e) {
        // ---- stage x[te] ----
        {
            int te = (e < TT) ? e : (TT - 1);
            #pragma unroll
            for (int rr = 0; rr < 2; ++rr) {
                int idx = tid + rr * 256;
                if (idx < 320) {
                    int r = idx / 5, j2 = idx - r * 5;
                    float2 v = *(const float2*)(x + (size_t)(rb0 + r) * 2560 + te * 10 + 2 * j2);
                    xs[(2 * j2) * 64 + r]     = v.x;
                    xs[(2 * j2 + 1) * 64 + r] = v.y;
                }
            }
        }
        __syncthreads();   // xs visible

        // ---- gate: all 32 producers at flag >= e (per-wave, dual-path) ----
        {
            const u32 tgt = (u32)e;
            u32 rdy;
            if (!safeMode) {
                rdy = mkrdy_fast(rs, flF, lane, tgt);
                int sp = 0;
                while (rdy != 0xFFFFFFFFu && ++sp < 4096)
                    rdy = mkrdy_fast(rs, flF, lane, tgt);
                if (rdy != 0xFFFFFFFFu) safeMode = 1;
            }
            if (safeMode) {
                rdy = mkrdy_safe(flS, lane, tgt);
                while (rdy != 0xFFFFFFFFu) {
                    __builtin_amdgcn_s_sleep(2);
                    rdy = mkrdy_safe(flS, lane, tgt);
                }
            }
            __builtin_amdgcn_sched_barrier(0);
        }
        WAITV(0);   // baseline: manual vmcnt counting starts at 0

        // ---- gemm: 8 k32-chunks; A sc0 from L2 h-ring, B from LDS ----
        const u32 vo0 = OB_H0HI + (u32)((((e + 1) & 1) * 8 + ib) * 32768);
        const u32 vo1 = OB_H0LO + (u32)((((e + 1) & 1) * 8 + ib) * 32768);
        const u32 vo2 = OB_H1HI + (u32)(((e & 1) * 8 + ib) * 32768);
        const u32 vo3 = OB_H1LO + (u32)(((e & 1) * 8 + ib) * 32768);

        bf16x8 fA[2][4];
        #define ISSUE(b, qc) { const u32 tB = (u32)((qc) * 4096) + oaB;   \
            ld16s(fA[b][0], rs, vo0 + tB);                                \
            ld16s(fA[b][1], rs, vo1 + tB);                                \
            ld16s(fA[b][2], rs, vo2 + tB);                                \
            ld16s(fA[b][3], rs, vo3 + tB); }
        ISSUE(0, 0)
        ISSUE(1, 1)

        // ---- x contribution + bias (VALU work covers first A-load latency) ----
        float xc[8];
        {
            int r = tid >> 2, up = tid & 3;
            #pragma unroll
            for (int j = 0; j < 8; ++j) xc[j] = b0r[j];
            #pragma unroll
            for (int i = 0; i < 10; ++i) {
                float xv = xs[i * 64 + r];
                #pragma unroll
                for (int j = 0; j < 8; ++j)
                    xc[j] += xv * ldsWx[i * 32 + up * 8 + j];
            }
        }

        f32x4 C0[2], C1[2];
        #pragma unroll
        for (int ct = 0; ct < 2; ++ct) {
            C0[ct] = (f32x4){0.f, 0.f, 0.f, 0.f};
            C1[ct] = (f32x4){0.f, 0.f, 0.f, 0.f};
        }

        #pragma unroll
        for (int q = 0; q < 8; ++q) {
            const int b = q & 1;
            bf16x8 wA[2][2], wB[2][2], wC[2][2];   // [hi/lo][col-tile]
            #pragma unroll
            for (int ct = 0; ct < 2; ++ct) {
                int rb = ct * 16 + l15;
                wA[0][ct] = bw[5 * ((0 * 8 + q) * 32 + rb) + quad];  // hh0 hi
                wA[1][ct] = bw[5 * ((1 * 8 + q) * 32 + rb) + quad];  // hh0 lo
                wB[0][ct] = bw[5 * ((2 * 8 + q) * 32 + rb) + quad];  // ih1 hi
                wB[1][ct] = bw[5 * ((3 * 8 + q) * 32 + rb) + quad];  // ih1 lo
                wC[0][ct] = bw[5 * ((4 * 8 + q) * 32 + rb) + quad];  // hh1 hi
                wC[1][ct] = bw[5 * ((5 * 8 + q) * 32 + rb) + quad];  // hh1 lo
            }
            // 2 chunks x 4 loads in flight; retire the oldest 4 (chunk q)
            if (q < 7) { WAITV(4); } else { WAITV(0); }
            bf16x8 a0h = fA[b][0], a0l = fA[b][1];
            bf16x8 a1h = fA[b][2], a1l = fA[b][3];
            #pragma unroll
            for (int ct = 0; ct < 2; ++ct) {
                // hi*hi + hi*lo + lo*hi (lo*lo dropped: <= 2^-18 relative)
                C0[ct] = __builtin_amdgcn_mfma_f32_16x16x32_bf16(a0h, wA[0][ct], C0[ct], 0, 0, 0);
                C0[ct] = __builtin_amdgcn_mfma_f32_16x16x32_bf16(a0h, wA[1][ct], C0[ct], 0, 0, 0);
                C0[ct] = __builtin_amdgcn_mfma_f32_16x16x32_bf16(a0l, wA[0][ct], C0[ct], 0, 0, 0);
                C1[ct] = __builtin_amdgcn_mfma_f32_16x16x32_bf16(a0h, wB[0][ct], C1[ct], 0, 0, 0);
                C1[ct] = __builtin_amdgcn_mfma_f32_16x16x32_bf16(a0h, wB[1][ct], C1[ct], 0, 0, 0);
                C1[ct] = __builtin_amdgcn_mfma_f32_16x16x32_bf16(a0l, wB[0][ct], C1[ct], 0, 0, 0);
                C1[ct] = __builtin_amdgcn_mfma_f32_16x16x32_bf16(a1h, wC[0][ct], C1[ct], 0, 0, 0);
                C1[ct] = __builtin_amdgcn_mfma_f32_16x16x32_bf16(a1h, wC[1][ct], C1[ct], 0, 0, 0);
                C1[ct] = __builtin_amdgcn_mfma_f32_16x16x32_bf16(a1l, wC[0][ct], C1[ct], 0, 0, 0);
            }
            if (q < 6) ISSUE(b, q + 2)
        }
        #undef ISSUE

        // ---- C/D frags -> scratch (D: col=lane&15, row=quad*4+reg) ----
        #pragma unroll
        for (int ct = 0; ct < 2; ++ct)
            #pragma unroll
            for (int reg = 0; reg < 4; ++reg) {
                int rr = wv * 16 + quad * 4 + reg;
                CS[rr * 33 + ct * 16 + l15]        = C0[ct][reg];
                CS[2112 + rr * 33 + ct * 16 + l15] = C1[ct][reg];
            }
        __syncthreads();

        // ---- eltwise (thread = row x unit-pair); pack + sc0 store into L2 ----
        {
            int r = tid >> 2, up = tid & 3;
            if (e < TT) {
                float h0n[2];
                #pragma unroll
                for (int s = 0; s < 2; ++s) {
                    int c4 = up * 8 + s * 4;
                    float gi = CS[r * 33 + c4 + 0] + xc[s * 4 + 0];
                    float gf = CS[r * 33 + c4 + 1] + xc[s * 4 + 1];
                    float gg = CS[r * 33 + c4 + 2] + xc[s * 4 + 2];
                    float go = CS[r * 33 + c4 + 3] + xc[s * 4 + 3];
                    float cn = sigf(gf) * c0s[s] + sigf(gi) * tanhfast(gg);
                    c0s[s] = cn;
                    h0n[s] = sigf(go) * tanhfast(cn);
                }
                u32 sb = (u32)(((e & 1) * 8 + ib) * 32768 + ik * 1024 + 4 * tid);
                st4s(rs, OB_H0HI + sb, (u32)bhi(h0n[0]) | ((u32)bhi(h0n[1]) << 16));
                st4s(rs, OB_H0LO + sb, (u32)blo(h0n[0]) | ((u32)blo(h0n[1]) << 16));
            }
            if (e > 0) {
                float h1n[2];
                #pragma unroll
                for (int s = 0; s < 2; ++s) {
                    int c4 = up * 8 + s * 4;
                    float gi = CS[2112 + r * 33 + c4 + 0] + b1r[s * 4 + 0];
                    float gf = CS[2112 + r * 33 + c4 + 1] + b1r[s * 4 + 1];
                    float gg = CS[2112 + r * 33 + c4 + 2] + b1r[s * 4 + 2];
                    float go = CS[2112 + r * 33 + c4 + 3] + b1r[s * 4 + 3];
                    float cn = sigf(gf) * c1s[s] + sigf(gi) * tanhfast(gg);
                    c1s[s] = cn;
                    h1n[s] = sigf(go) * tanhfast(cn);
                }
                u32 sb = (u32)((((e + 1) & 1) * 8 + ib) * 32768 + ik * 1024 + 4 * tid);
                st4s(rs, OB_H1HI + sb, (u32)bhi(h1n[0]) | ((u32)bhi(h1n[1]) << 16));
                st4s(rs, OB_H1LO + sb, (u32)blo(h1n[0]) | ((u32)blo(h1n[1]) << 16));
            }
        }
        WAITV(0);          // h stores retired at L2 (coherence point)
        __syncthreads();   // all threads' stores done
        if (tid == 0) {
            st4s(rs, flF + (u32)(ik * 4), (u32)(e + 1));      // fast flag (sc0)
            __hip_atomic_store(flSw, (u32)(e + 1),
                               __ATOMIC_RELAXED, __HIP_MEMORY_SCOPE_AGENT);
        }
    }

    // ---- head: y[b] = h1[255] . Wlin + blin (slot 1, tile layout) ----
    if (ik == 0) {
        {
            const u32 tgt = (u32)(TT + 1);
            u32 rdy;
            if (!safeMode) {
                rdy = mkrdy_fast(rs, flF, lane, tgt);
                int sp = 0;
                while (rdy != 0xFFFFFFFFu && ++sp < 4096)
                    rdy = mkrdy_fast(rs, flF, lane, tgt);
                if (rdy != 0xFFFFFFFFu) safeMode = 1;
            }
            if (safeMode) {
                rdy = mkrdy_safe(flS, lane, tgt);
                while (rdy != 0xFFFFFFFFu) {
                    __builtin_amdgcn_s_sleep(2);
                    rdy = mkrdy_safe(flS, lane, tgt);
                }
            }
            __builtin_amdgcn_sched_barrier(0);
        }
        int r = tid >> 2, q4 = tid & 3;
        const u32 bh_ = OB_H1HI + (u32)((8 + ib) * 32768);
        const u32 bl_ = OB_H1LO + (u32)((8 + ib) * 32768);
        float sacc = 0.f;
        #pragma unroll 1
        for (int kk = 0; kk < 64; kk += 8) {
            u32 hw4[4], lw4[4];
            #pragma unroll
            for (int t = 0; t < 4; ++t) {
                int k = q4 * 64 + kk + 2 * t;
                u32 sa = (u32)(((k >> 3) * 512 + r * 8 + (k & 7)) * 2);
                hw4[t] = ld4s(rs, bh_ + sa);
                lw4[t] = ld4s(rs, bl_ + sa);
            }
            WAITV(0);
            #pragma unroll
            for (int t = 0; t < 4; ++t) {
                int k = q4 * 64 + kk + 2 * t;
                sacc += (bff(hw4[t] & 0xFFFFu) + bff(lw4[t] & 0xFFFFu)) * Wlin[k];
                sacc += (bff(hw4[t] >> 16)     + bff(lw4[t] >> 16))     * Wlin[k + 1];
            }
        }
        sacc += __shfl_down(sacc, 2, 4);
        sacc += __shfl_down(sacc, 1, 4);
        if (q4 == 0) out[rb0 + r] = sacc + blin[0];
    }
}

// ---------------------------------------------------------------------------
extern "C" void kernel_launch(void* const* d_in, const int* in_sizes, int n_in,
                              void* d_out, int out_size, void* d_ws, size_t ws_size,
                              hipStream_t stream) {
    const float* x     = (const float*)d_in[0];
    const float* W_ih0 = (const float*)d_in[1];
    const float* W_hh0 = (const float*)d_in[2];
    const float* b_ih0 = (const float*)d_in[3];
    const float* b_hh0 = (const float*)d_in[4];
    const float* W_ih1 = (const float*)d_in[5];
    const float* W_hh1 = (const float*)d_in[6];
    const float* b_ih1 = (const float*)d_in[7];
    const float* b_hh1 = (const float*)d_in[8];
    const float* W_lin = (const float*)d_in[9];
    const float* b_lin = (const float*)d_in[10];
    float* out = (float*)d_out;
    char* wsb  = (char*)d_ws;

    // zero h ring planes + flag region (ws re-poisoned before every timed launch)
    hipMemsetAsync(wsb + BOFF_H0HI, 0, 4 * 524288 + 131584, stream);

    split_w<<<3072, 256, 0, stream>>>(W_hh0, W_ih1, W_hh1,
                                      (unsigned short*)(wsb + BOFF_WT));
    transpose_gi<<<40, 256, 0, stream>>>(W_ih0, (float*)(wsb + BOFF_WX), 10);

    lstm_mfma<<<256, 256, 0, stream>>>(x, b_ih0, b_hh0, b_ih1, b_hh1,
                                       W_lin, b_lin, wsb, out);
}